// Round 5
// baseline (106.951 us; speedup 1.0000x reference)
//
#include <hip/hip_runtime.h>
#include <hip/hip_fp16.h>

#define CDIM  512
#define ROWS  65536
#define NWG   128      // WGs per j-class
#define TILES 16       // 32-row tiles per WG: NWG*32*TILES = ROWS

typedef _Float16 half8  __attribute__((ext_vector_type(8)));
typedef __fp16   fp16x2 __attribute__((ext_vector_type(2)));
typedef float    f32x16 __attribute__((ext_vector_type(16)));

// async global->LDS, 16B per lane; LDS dest = wave-uniform base + lane*16
#define GLD_LDS16(gp, lp) __builtin_amdgcn_global_load_lds( \
    (const __attribute__((address_space(1))) unsigned int*)(gp), \
    (__attribute__((address_space(3))) unsigned int*)(lp), 16, 0, 0)

// ---------------- K1a: v[j] = relu(Q . Wq[j,:] + bq[j]) * Wout[j/64] / 8 ----------------
__global__ void qproj_kernel(const float* __restrict__ Q, const float* __restrict__ Wq,
                             const float* __restrict__ bq, const float* __restrict__ Wout,
                             float* __restrict__ v) {
    __shared__ float qs[CDIM];
    const int t = threadIdx.x;
    qs[t] = Q[t]; qs[t + 256] = Q[t + 256];
    __syncthreads();
    const int jj  = t >> 4;
    const int sub = t & 15;
    const int j   = blockIdx.x * 16 + jj;
    const float4* w4 = (const float4*)(Wq + (size_t)j * CDIM + sub * 32);
    const float4* q4 = (const float4*)(qs + sub * 32);
    float s = 0.f;
    #pragma unroll
    for (int i = 0; i < 8; ++i) {
        float4 w = w4[i]; float4 q = q4[i];
        s = fmaf(w.x, q.x, s); s = fmaf(w.y, q.y, s);
        s = fmaf(w.z, q.z, s); s = fmaf(w.w, q.w, s);
    }
    s += __shfl_xor(s, 1); s += __shfl_xor(s, 2);
    s += __shfl_xor(s, 4); s += __shfl_xor(s, 8);
    if (sub == 0) {
        s += bq[j];
        s = fmaxf(s, 0.f);
        v[j] = s * Wout[j >> 6] * 0.125f;   // 1/sqrt(64) folded; bout dropped (shift-invariant)
    }
}

// ---------------- K1b: Wk -> fp16 B-fragments [jb 0..15][kc 0..31][lane 0..63][8 halfs] ----
// Fragment (jb,kc), lane l: B[k = kc*16 + (l>>5)*8 + e][j = jb*32 + (l&31)]
__global__ void wkfrag_kernel(const float* __restrict__ Wk, _Float16* __restrict__ Wkf) {
    const int gid = blockIdx.x * 256 + threadIdx.x;   // 32768 half8 slots
    const int jb  = gid >> 11;
    const int kc  = (gid >> 6) & 31;
    const int l   = gid & 63;
    const int j   = jb * 32 + (l & 31);
    const int k   = kc * 16 + (l >> 5) * 8;
    const float* src = Wk + (size_t)j * CDIM + k;
    float4 f0 = *(const float4*)(src);
    float4 f1 = *(const float4*)(src + 4);
    half8 h;
    h[0]=(_Float16)f0.x; h[1]=(_Float16)f0.y; h[2]=(_Float16)f0.z; h[3]=(_Float16)f0.w;
    h[4]=(_Float16)f1.x; h[5]=(_Float16)f1.y; h[6]=(_Float16)f1.z; h[7]=(_Float16)f1.w;
    *(half8*)(Wkf + (size_t)gid * 8) = h;
}

// ---------------- K2: Wk-resident score kernel, fp32 K staged via global_load_lds ----------
// grid (NWG, 2): class c owns j in [c*256, c*256+256); 8 waves x 32 j each (B in 128 regs).
// K staged RAW FP32 (async DMA, no VGPR roundtrip), double-buffered 2x64KB.
// Swizzle: LDS chunk (r, C) holds global chunk (r, C^r); reads XOR the same -> conflict-free.
__global__ __launch_bounds__(512, 2) void score_kernel(
    const float* __restrict__ Kmat, const _Float16* __restrict__ Wkf,
    const float* __restrict__ bk, const float* __restrict__ v,
    float* __restrict__ partial2)
{
    __shared__ alignas(16) float stage[2][32 * 512];   // 2 x 64KB fp32
    __shared__ float scratch[2][8][32];                // per-tile cross-wave row partials

    const int tid  = threadIdx.x;
    const int lane = tid & 63;
    const int wave = tid >> 6;
    const int l31  = lane & 31;
    const int lhi  = lane >> 5;
    const int cls  = blockIdx.y;
    const int jb   = cls * 8 + wave;

    // ---- B prologue: 32 resident fragments (full depth for this wave's 32 j's) ----
    half8 B[32];
    const half8* bsrc = (const half8*)Wkf + ((size_t)jb * 32) * 64 + lane;
    #pragma unroll
    for (int kc = 0; kc < 32; ++kc) B[kc] = bsrc[kc * 64];
    const int jmy = jb * 32 + l31;
    const float bj = bk[jmy];
    const float vj = v[jmy];

    const int rowbase0 = blockIdx.x * (TILES * 32);
    float* pbase = partial2 + (size_t)cls * ROWS;

    // staging geometry (per wave-iter): row r = it*4 + (wave>>1), chunks C = (wave&1)*64 + lane
    const int srow = wave >> 1;
    const int scol = (wave & 1) << 6;

    // ---- prologue: stage tile 0 into buf 0 ----
    {
        const float* tb = Kmat + (size_t)rowbase0 * CDIM;
        #pragma unroll
        for (int it = 0; it < 8; ++it) {
            const int r = it * 4 + srow;
            const int c = (scol + lane) ^ r;                       // source pre-swizzle
            GLD_LDS16(tb + (size_t)r * CDIM + c * 4,
                      &stage[0][(it * 512 + wave * 64) * 4]);
        }
    }
    __syncthreads();

    for (int t = 0; t < TILES; ++t) {
        const int cur = t & 1;

        // async stage of tile t+1 (issued before compute; drains at the tile-end barrier)
        if (t + 1 < TILES) {
            const float* tb = Kmat + (size_t)(rowbase0 + (t + 1) * 32) * CDIM;
            float* db = &stage[cur ^ 1][0];
            #pragma unroll
            for (int it = 0; it < 8; ++it) {
                const int r = it * 4 + srow;
                const int c = (scol + lane) ^ r;
                GLD_LDS16(tb + (size_t)r * CDIM + c * 4,
                          db + (it * 512 + wave * 64) * 4);
            }
        }

        // cross-wave summer for tile t-1 (wave 0 only)
        if (t > 0 && tid < 32) {
            float s = 0.f;
            #pragma unroll
            for (int w = 0; w < 8; ++w) s += scratch[(t - 1) & 1][w][tid];
            pbase[rowbase0 + (t - 1) * 32 + tid] = s;
        }

        // ---- compute: 32 k-chunks, 2 independent MFMA chains; cvt fp32->fp16 at read ----
        const float* sb = &stage[cur][0];
        f32x16 acc0, acc1;
        #pragma unroll
        for (int r = 0; r < 16; ++r) { acc0[r] = 0.f; acc1[r] = 0.f; }
        #pragma unroll
        for (int kc = 0; kc < 32; kc += 2) {
            const int cb0 = kc * 4 + lhi * 2;
            const int cb1 = cb0 + 4;
            float4 f00 = *(const float4*)(sb + ((l31 * 128 + ((cb0    ) ^ l31)) << 2));
            float4 f01 = *(const float4*)(sb + ((l31 * 128 + ((cb0 + 1) ^ l31)) << 2));
            float4 f10 = *(const float4*)(sb + ((l31 * 128 + ((cb1    ) ^ l31)) << 2));
            float4 f11 = *(const float4*)(sb + ((l31 * 128 + ((cb1 + 1) ^ l31)) << 2));
            union { fp16x2 h2[4]; half8 h8; } u0, u1;
            u0.h2[0] = __builtin_amdgcn_cvt_pkrtz(f00.x, f00.y);
            u0.h2[1] = __builtin_amdgcn_cvt_pkrtz(f00.z, f00.w);
            u0.h2[2] = __builtin_amdgcn_cvt_pkrtz(f01.x, f01.y);
            u0.h2[3] = __builtin_amdgcn_cvt_pkrtz(f01.z, f01.w);
            u1.h2[0] = __builtin_amdgcn_cvt_pkrtz(f10.x, f10.y);
            u1.h2[1] = __builtin_amdgcn_cvt_pkrtz(f10.z, f10.w);
            u1.h2[2] = __builtin_amdgcn_cvt_pkrtz(f11.x, f11.y);
            u1.h2[3] = __builtin_amdgcn_cvt_pkrtz(f11.z, f11.w);
            acc0 = __builtin_amdgcn_mfma_f32_32x32x16_f16(u0.h8, B[kc],     acc0, 0, 0, 0);
            acc1 = __builtin_amdgcn_mfma_f32_32x32x16_f16(u1.h8, B[kc + 1], acc1, 0, 0, 0);
        }

        // ---- epilogue: relu + v-weight, reduce over the 32 j-lanes ----
        float part[16];
        #pragma unroll
        for (int r = 0; r < 16; ++r) {
            float x = fmaxf(acc0[r] + acc1[r] + bj, 0.f) * vj;
            x += __shfl_xor(x, 1);
            x += __shfl_xor(x, 2);
            x += __shfl_xor(x, 4);
            x += __shfl_xor(x, 8);
            x += __shfl_xor(x, 16);
            part[r] = x;
        }
        if (l31 == 0) {
            #pragma unroll
            for (int r = 0; r < 16; ++r)
                scratch[cur][wave][(r & 3) + 8 * (r >> 2) + 4 * lhi] = part[r];
        }

        __syncthreads();   // drains gload_lds (vmcnt) + LDS ops before buffer swap
    }

    // drain: summer for the last tile
    if (tid < 32) {
        float s = 0.f;
        #pragma unroll
        for (int w = 0; w < 8; ++w) s += scratch[(TILES - 1) & 1][w][tid];
        pbase[rowbase0 + (TILES - 1) * 32 + tid] = s;
    }
}

// ---------------- K3: merge classes, store logits, per-block exp-sum ----------------
__global__ void expsum_kernel(const float* __restrict__ partial2, float* __restrict__ logits,
                              float* __restrict__ blocksum) {
    __shared__ float red[256];
    const int t = threadIdx.x;
    const int row = blockIdx.x * 256 + t;
    const float lg = partial2[row] + partial2[ROWS + row];
    logits[row] = lg;
    red[t] = expf(lg);
    __syncthreads();
    for (int s = 128; s > 0; s >>= 1) {
        if (t < s) red[t] += red[t + s];
        __syncthreads();
    }
    if (t == 0) blocksum[blockIdx.x] = red[0];
}

// ---------------- K4: normalize ----------------
__global__ void norm_kernel(const float* __restrict__ logits, const float* __restrict__ blocksum,
                            float* __restrict__ out) {
    __shared__ float red[256];
    const int t = threadIdx.x;
    red[t] = blocksum[t];
    __syncthreads();
    for (int s = 128; s > 0; s >>= 1) {
        if (t < s) red[t] += red[t + s];
        __syncthreads();
    }
    const float zinv = 1.0f / red[0];
    const int i = blockIdx.x * 256 + t;
    out[i] = expf(logits[i]) * zinv;
}

extern "C" void kernel_launch(void* const* d_in, const int* in_sizes, int n_in,
                              void* d_out, int out_size, void* d_ws, size_t ws_size,
                              hipStream_t stream) {
    const float* Q    = (const float*)d_in[0];
    const float* Kmat = (const float*)d_in[1];
    const float* Wq   = (const float*)d_in[2];
    const float* bq   = (const float*)d_in[3];
    const float* Wk   = (const float*)d_in[4];
    const float* bk   = (const float*)d_in[5];
    const float* Wout = (const float*)d_in[6];
    float* out = (float*)d_out;

    char* ws = (char*)d_ws;
    _Float16* Wkf   = (_Float16*)(ws);                // 524288 B
    float* v        = (float*)(ws + 524288);          //   2048 B
    float* partial2 = (float*)(ws + 526336);          // 524288 B (2 classes x 65536)
    float* logits   = (float*)(ws + 1050624);         // 262144 B
    float* blocksum = (float*)(ws + 1312768);         //   1024 B

    hipLaunchKernelGGL(qproj_kernel,  dim3(32),     dim3(256), 0, stream, Q, Wq, bq, Wout, v);
    hipLaunchKernelGGL(wkfrag_kernel, dim3(128),    dim3(256), 0, stream, Wk, Wkf);
    hipLaunchKernelGGL(score_kernel,  dim3(NWG, 2), dim3(512), 0, stream, Kmat, Wkf, bk, v, partial2);
    hipLaunchKernelGGL(expsum_kernel, dim3(256),    dim3(256), 0, stream, partial2, logits, blocksum);
    hipLaunchKernelGGL(norm_kernel,   dim3(256),    dim3(256), 0, stream, logits, blocksum, out);
}

// Round 6
// 64.426 us; speedup vs baseline: 1.6601x; 1.6601x over previous
//
#include <hip/hip_runtime.h>
#include <hip/hip_fp16.h>

#define CDIM  512
#define ROWS  65536
#define TILES 16
#define GX    128      // GX * TILES * 32 = 65536 rows
#define NCLS  4        // j-classes: 4 x (4 waves x 32 j) = 512

typedef _Float16 half8  __attribute__((ext_vector_type(8)));
typedef __fp16   fp16x2 __attribute__((ext_vector_type(2)));
typedef float    f32x16 __attribute__((ext_vector_type(16)));

// ---------------- K1a: v[j] = relu(Q . Wq[j,:] + bq[j]) * Wout[j/64] / 8 ----------------
__global__ void qproj_kernel(const float* __restrict__ Q, const float* __restrict__ Wq,
                             const float* __restrict__ bq, const float* __restrict__ Wout,
                             float* __restrict__ v) {
    __shared__ float qs[CDIM];
    const int t = threadIdx.x;
    qs[t] = Q[t]; qs[t + 256] = Q[t + 256];
    __syncthreads();
    const int jj  = t >> 4;
    const int sub = t & 15;
    const int j   = blockIdx.x * 16 + jj;
    const float4* w4 = (const float4*)(Wq + (size_t)j * CDIM + sub * 32);
    const float4* q4 = (const float4*)(qs + sub * 32);
    float s = 0.f;
    #pragma unroll
    for (int i = 0; i < 8; ++i) {
        float4 w = w4[i]; float4 q = q4[i];
        s = fmaf(w.x, q.x, s); s = fmaf(w.y, q.y, s);
        s = fmaf(w.z, q.z, s); s = fmaf(w.w, q.w, s);
    }
    s += __shfl_xor(s, 1); s += __shfl_xor(s, 2);
    s += __shfl_xor(s, 4); s += __shfl_xor(s, 8);
    if (sub == 0) {
        s += bq[j];
        s = fmaxf(s, 0.f);
        v[j] = s * Wout[j >> 6] * 0.125f;   // 1/sqrt(64) folded; bout dropped (shift-invariant)
    }
}

// ---------------- K1b: Wk -> fp16 B-fragments [jb 0..15][kc 0..31][lane 0..63][8 halfs] ----
// Fragment (jb,kc), lane l: B[k = kc*16 + (l>>5)*8 + e][j = jb*32 + (l&31)]
__global__ void wkfrag_kernel(const float* __restrict__ Wk, _Float16* __restrict__ Wkf) {
    const int gid = blockIdx.x * 256 + threadIdx.x;   // 32768 half8 slots
    const int jb  = gid >> 11;
    const int kc  = (gid >> 6) & 31;
    const int l   = gid & 63;
    const int j   = jb * 32 + (l & 31);
    const int k   = kc * 16 + (l >> 5) * 8;
    const float* src = Wk + (size_t)j * CDIM + k;
    float4 f0 = *(const float4*)(src);
    float4 f1 = *(const float4*)(src + 4);
    half8 h;
    h[0]=(_Float16)f0.x; h[1]=(_Float16)f0.y; h[2]=(_Float16)f0.z; h[3]=(_Float16)f0.w;
    h[4]=(_Float16)f1.x; h[5]=(_Float16)f1.y; h[6]=(_Float16)f1.z; h[7]=(_Float16)f1.w;
    *(half8*)(Wkf + (size_t)gid * 8) = h;
}

// ---------------- K2: 4-wave WG, B-in-regs (32 j/wave), K staged fp16, 2 WG/CU ----------
// grid (GX, NCLS). Class c covers j in [c*128, c*128+128); wave w owns jb = c*4+w.
// Per tile: 32 rows staged fp16 (reg-staged, cvt_pkrtz, XOR-swizzled chunks), all 4 waves
// read the full tile against their resident B. Fold-tree epilogue (16 shfl).
__global__ __launch_bounds__(256, 2) void score_kernel(
    const float* __restrict__ Kmat, const _Float16* __restrict__ Wkf,
    const float* __restrict__ bk, const float* __restrict__ v,
    float* __restrict__ partial2)
{
    __shared__ alignas(16) _Float16 stage[2][32][512];   // 2 x 32KB
    __shared__ float scratch2[2][4][32];                 // per-tile per-wave row sums

    const int tid  = threadIdx.x;
    const int lane = tid & 63;
    const int wave = tid >> 6;
    const int l31  = lane & 31;
    const int lhi  = lane >> 5;
    const int cls  = blockIdx.y;
    const int jb   = cls * 4 + wave;

    // ---- B prologue: 32 resident fragments (full depth, this wave's 32 j's) ----
    half8 B[32];
    const half8* bsrc = (const half8*)Wkf + (size_t)jb * 2048 + lane;
    #pragma unroll
    for (int kc = 0; kc < 32; ++kc) B[kc] = bsrc[kc * 64];
    const int jmy = jb * 32 + l31;
    const float bj = bk[jmy];
    const float vj = v[jmy];

    const int rowbase = blockIdx.x * (TILES * 32);
    float* pbase = partial2 + (size_t)cls * ROWS;

    // ---- prologue: stage tile 0 (wave w stages tile-rows w*8 .. w*8+7) ----
    {
        #pragma unroll
        for (int i = 0; i < 8; ++i) {
            const int rt = wave * 8 + i;
            const float* src = Kmat + (size_t)(rowbase + rt) * CDIM + lane * 8;
            float4 a = *(const float4*)(src);
            float4 b = *(const float4*)(src + 4);
            union { fp16x2 h2[4]; half8 h8; } u;
            u.h2[0] = __builtin_amdgcn_cvt_pkrtz(a.x, a.y);
            u.h2[1] = __builtin_amdgcn_cvt_pkrtz(a.z, a.w);
            u.h2[2] = __builtin_amdgcn_cvt_pkrtz(b.x, b.y);
            u.h2[3] = __builtin_amdgcn_cvt_pkrtz(b.z, b.w);
            const int slot = lane ^ (rt & 7);
            *(half8*)(&stage[0][rt][slot * 8]) = u.h8;
        }
    }
    __syncthreads();

    for (int t = 0; t < TILES; ++t) {
        const int cur = t & 1;
        const bool pf = (t + 1 < TILES);

        // cross-wave summer for tile t-1
        if (t > 0 && tid < 32) {
            const int pt = (t - 1) & 1;
            float s = scratch2[pt][0][tid] + scratch2[pt][1][tid]
                    + scratch2[pt][2][tid] + scratch2[pt][3][tid];
            pbase[rowbase + (t - 1) * 32 + tid] = s;
        }

        f32x16 acc0, acc1;
        #pragma unroll
        for (int r = 0; r < 16; ++r) { acc0[r] = 0.f; acc1[r] = 0.f; }

        const _Float16* sb = &stage[cur][0][0];

        // ---- half 0: issue loads (tile t+1, rows w*8..w*8+3), compute kc 0..15 ----
        float4 ga0[4], gb0[4];
        if (pf) {
            const int rs = rowbase + (t + 1) * 32;
            #pragma unroll
            for (int i = 0; i < 4; ++i) {
                const float* src = Kmat + (size_t)(rs + wave * 8 + i) * CDIM + lane * 8;
                ga0[i] = *(const float4*)(src);
                gb0[i] = *(const float4*)(src + 4);
            }
        }
        __builtin_amdgcn_sched_barrier(0);

        #pragma unroll
        for (int kc = 0; kc < 16; kc += 2) {
            const int ch0 = (kc * 2 + lhi) ^ (l31 & 7);
            const int ch1 = ((kc + 1) * 2 + lhi) ^ (l31 & 7);
            half8 a0 = *(const half8*)(sb + l31 * 512 + ch0 * 8);
            half8 a1 = *(const half8*)(sb + l31 * 512 + ch1 * 8);
            acc0 = __builtin_amdgcn_mfma_f32_32x32x16_f16(a0, B[kc],     acc0, 0, 0, 0);
            acc1 = __builtin_amdgcn_mfma_f32_32x32x16_f16(a1, B[kc + 1], acc1, 0, 0, 0);
        }

        // write-late half 0 into the other buffer
        if (pf) {
            #pragma unroll
            for (int i = 0; i < 4; ++i) {
                const int rt = wave * 8 + i;
                union { fp16x2 h2[4]; half8 h8; } u;
                u.h2[0] = __builtin_amdgcn_cvt_pkrtz(ga0[i].x, ga0[i].y);
                u.h2[1] = __builtin_amdgcn_cvt_pkrtz(ga0[i].z, ga0[i].w);
                u.h2[2] = __builtin_amdgcn_cvt_pkrtz(gb0[i].x, gb0[i].y);
                u.h2[3] = __builtin_amdgcn_cvt_pkrtz(gb0[i].z, gb0[i].w);
                const int slot = lane ^ (rt & 7);
                *(half8*)(&stage[cur ^ 1][rt][slot * 8]) = u.h8;
            }
        }

        // ---- half 1: issue loads (rows w*8+4..w*8+7), compute kc 16..31 ----
        float4 ga1[4], gb1[4];
        if (pf) {
            const int rs = rowbase + (t + 1) * 32;
            #pragma unroll
            for (int i = 0; i < 4; ++i) {
                const float* src = Kmat + (size_t)(rs + wave * 8 + 4 + i) * CDIM + lane * 8;
                ga1[i] = *(const float4*)(src);
                gb1[i] = *(const float4*)(src + 4);
            }
        }
        __builtin_amdgcn_sched_barrier(0);

        #pragma unroll
        for (int kc = 16; kc < 32; kc += 2) {
            const int ch0 = (kc * 2 + lhi) ^ (l31 & 7);
            const int ch1 = ((kc + 1) * 2 + lhi) ^ (l31 & 7);
            half8 a0 = *(const half8*)(sb + l31 * 512 + ch0 * 8);
            half8 a1 = *(const half8*)(sb + l31 * 512 + ch1 * 8);
            acc0 = __builtin_amdgcn_mfma_f32_32x32x16_f16(a0, B[kc],     acc0, 0, 0, 0);
            acc1 = __builtin_amdgcn_mfma_f32_32x32x16_f16(a1, B[kc + 1], acc1, 0, 0, 0);
        }

        if (pf) {
            #pragma unroll
            for (int i = 0; i < 4; ++i) {
                const int rt = wave * 8 + 4 + i;
                union { fp16x2 h2[4]; half8 h8; } u;
                u.h2[0] = __builtin_amdgcn_cvt_pkrtz(ga1[i].x, ga1[i].y);
                u.h2[1] = __builtin_amdgcn_cvt_pkrtz(ga1[i].z, ga1[i].w);
                u.h2[2] = __builtin_amdgcn_cvt_pkrtz(gb1[i].x, gb1[i].y);
                u.h2[3] = __builtin_amdgcn_cvt_pkrtz(gb1[i].z, gb1[i].w);
                const int slot = lane ^ (rt & 7);
                *(half8*)(&stage[cur ^ 1][rt][slot * 8]) = u.h8;
            }
        }

        // ---- epilogue: relu + v-weight, fold-tree reduce over 32 j-lanes (16 shfl) ----
        float x[16];
        #pragma unroll
        for (int r = 0; r < 16; ++r)
            x[r] = fmaxf(acc0[r] + acc1[r] + bj, 0.f) * vj;

        float q0[8];
        #pragma unroll
        for (int i = 0; i < 8; ++i) {
            const bool b = lane & 1;
            float keep = b ? x[i + 8] : x[i];
            float send = b ? x[i] : x[i + 8];
            q0[i] = keep + __shfl_xor(send, 1);
        }
        float q1[4];
        #pragma unroll
        for (int i = 0; i < 4; ++i) {
            const bool b = lane & 2;
            float keep = b ? q0[i + 4] : q0[i];
            float send = b ? q0[i] : q0[i + 4];
            q1[i] = keep + __shfl_xor(send, 2);
        }
        float q2[2];
        #pragma unroll
        for (int i = 0; i < 2; ++i) {
            const bool b = lane & 4;
            float keep = b ? q1[i + 2] : q1[i];
            float send = b ? q1[i] : q1[i + 2];
            q2[i] = keep + __shfl_xor(send, 4);
        }
        float q3;
        {
            const bool b = lane & 8;
            float keep = b ? q2[1] : q2[0];
            float send = b ? q2[0] : q2[1];
            q3 = keep + __shfl_xor(send, 8);
        }
        float s = q3 + __shfl_xor(q3, 16);
        if (l31 < 16) {
            const int r   = ((l31 & 1) << 3) | ((l31 & 2) << 1) | ((l31 & 4) >> 1) | ((l31 & 8) >> 3);
            const int row = (r & 3) + 8 * (r >> 2) + 4 * lhi;
            scratch2[cur][wave][row] = s;
        }

        __syncthreads();
    }

    // drain: summer for the last tile
    if (tid < 32) {
        const int pt = (TILES - 1) & 1;
        float s = scratch2[pt][0][tid] + scratch2[pt][1][tid]
                + scratch2[pt][2][tid] + scratch2[pt][3][tid];
        pbase[rowbase + (TILES - 1) * 32 + tid] = s;
    }
}

// ---------------- K3: merge 4 classes, store logits, per-block exp-sum ----------------
__global__ void expsum_kernel(const float* __restrict__ partial2, float* __restrict__ logits,
                              float* __restrict__ blocksum) {
    __shared__ float red[256];
    const int t = threadIdx.x;
    const int row = blockIdx.x * 256 + t;
    const float lg = partial2[row] + partial2[ROWS + row]
                   + partial2[2 * ROWS + row] + partial2[3 * ROWS + row];
    logits[row] = lg;
    red[t] = expf(lg);
    __syncthreads();
    for (int s = 128; s > 0; s >>= 1) {
        if (t < s) red[t] += red[t + s];
        __syncthreads();
    }
    if (t == 0) blocksum[blockIdx.x] = red[0];
}

// ---------------- K4: normalize ----------------
__global__ void norm_kernel(const float* __restrict__ logits, const float* __restrict__ blocksum,
                            float* __restrict__ out) {
    __shared__ float red[256];
    const int t = threadIdx.x;
    red[t] = blocksum[t];
    __syncthreads();
    for (int s = 128; s > 0; s >>= 1) {
        if (t < s) red[t] += red[t + s];
        __syncthreads();
    }
    const float zinv = 1.0f / red[0];
    const int i = blockIdx.x * 256 + t;
    out[i] = expf(logits[i]) * zinv;
}

extern "C" void kernel_launch(void* const* d_in, const int* in_sizes, int n_in,
                              void* d_out, int out_size, void* d_ws, size_t ws_size,
                              hipStream_t stream) {
    const float* Q    = (const float*)d_in[0];
    const float* Kmat = (const float*)d_in[1];
    const float* Wq   = (const float*)d_in[2];
    const float* bq   = (const float*)d_in[3];
    const float* Wk   = (const float*)d_in[4];
    const float* bk   = (const float*)d_in[5];
    const float* Wout = (const float*)d_in[6];
    float* out = (float*)d_out;

    char* ws = (char*)d_ws;
    _Float16* Wkf   = (_Float16*)(ws);                // 524288 B
    float* v        = (float*)(ws + 524288);          //   2048 B
    float* partial2 = (float*)(ws + 526336);          // 1048576 B (4 classes x 65536)
    float* logits   = (float*)(ws + 1574912);         // 262144 B
    float* blocksum = (float*)(ws + 1837056);         //   1024 B

    hipLaunchKernelGGL(qproj_kernel,  dim3(32),        dim3(256), 0, stream, Q, Wq, bq, Wout, v);
    hipLaunchKernelGGL(wkfrag_kernel, dim3(128),       dim3(256), 0, stream, Wk, Wkf);
    hipLaunchKernelGGL(score_kernel,  dim3(GX, NCLS),  dim3(256), 0, stream, Kmat, Wkf, bk, v, partial2);
    hipLaunchKernelGGL(expsum_kernel, dim3(256),       dim3(256), 0, stream, partial2, logits, blocksum);
    hipLaunchKernelGGL(norm_kernel,   dim3(256),       dim3(256), 0, stream, logits, blocksum, out);
}